// Round 6
// baseline (387.790 us; speedup 1.0000x reference)
//
#include <hip/hip_runtime.h>
#include <math.h>

// Shapes (fixed): q(8,256,128,128) c_t(8,256,512) W_a(512,256) W_p(256,512) V_p(2,256)
#define Bq 8
#define Tt 256
#define Dd 256
#define Hh 128
#define Ww 128
#define Cc 512
#define HW (Hh*Ww)
#define NBT (Bq*Tt)   // 2048 tokens

__device__ __forceinline__ float lane_bcast(float x, int l) {
    return __uint_as_float(__builtin_amdgcn_readlane(__float_as_uint(x), l));
}

// ---------------- Kernel 0: transpose W_p (256x512) -> WpT (512x256) ------
__global__ __launch_bounds__(256) void transpose_wp(
    const float* __restrict__ W_p, float* __restrict__ WpT)
{
    __shared__ float tile[32][33];
    const int bx = blockIdx.x;            // c tile (16)
    const int by = blockIdx.y;            // p tile (8)
    const int lx = threadIdx.x & 31, ly = threadIdx.x >> 5;   // 32 x 8
#pragma unroll
    for (int j = 0; j < 4; j++) {
        int p = by * 32 + ly + j * 8;
        tile[ly + j * 8][lx] = W_p[(size_t)p * Cc + bx * 32 + lx];
    }
    __syncthreads();
#pragma unroll
    for (int j = 0; j < 4; j++) {
        int c = bx * 32 + ly + j * 8;
        WpT[(size_t)c * 256 + by * 32 + lx] = tile[lx][ly + j * 8];
    }
}

// ---------------- Kernel 1: u = c_t@W_a, p_t = 128*sig(V_p tanh(W_p c)) ---
// Proven round-0 form: TOK=8 -> 256 blocks (1/CU, 8 waves), ~15 us.
#define TOK 8
__global__ __launch_bounds__(512) void prep_kernel(
    const float* __restrict__ c_t,   // (NBT, 512)
    const float* __restrict__ W_a,   // (512, 256)  [c][d]
    const float* __restrict__ WpT,   // (512, 256)  [c][p]
    const float* __restrict__ V_p,   // (2, 256)
    float* __restrict__ u_ws,        // (NBT, 256)
    float* __restrict__ p_ws)        // (NBT, 2)
{
    __shared__ float y0s[TOK][256];
    __shared__ float y1s[TOK][256];
    const int tid  = threadIdx.x;
    const int o    = tid & 255;
    const int half = tid >> 8;
    const int ln   = tid & 63;
    const int bt0  = blockIdx.x * TOK;

    const float* Wcol = (half ? WpT : W_a) + o;   // column o, stride 256
    const float* ctb  = c_t + (size_t)bt0 * Cc;

    float acc[TOK];
#pragma unroll
    for (int t = 0; t < TOK; t++) acc[t] = 0.f;

    float ctr[TOK], ctn[TOK];
#pragma unroll
    for (int t = 0; t < TOK; t++) ctr[t] = ctb[t * Cc + ln];

#pragma unroll
    for (int c0 = 0; c0 < Cc; c0 += 64) {
        if (c0 + 64 < Cc) {
#pragma unroll
            for (int t = 0; t < TOK; t++) ctn[t] = ctb[t * Cc + c0 + 64 + ln];
        }
#pragma unroll
        for (int cc8 = 0; cc8 < 64; cc8 += 8) {
            float w[8];
#pragma unroll
            for (int j = 0; j < 8; j++)
                w[j] = Wcol[(size_t)(c0 + cc8 + j) * 256];
#pragma unroll
            for (int j = 0; j < 8; j++) {
#pragma unroll
                for (int t = 0; t < TOK; t++)
                    acc[t] = fmaf(lane_bcast(ctr[t], cc8 + j), w[j], acc[t]);
            }
        }
#pragma unroll
        for (int t = 0; t < TOK; t++) ctr[t] = ctn[t];
    }

    if (half == 0) {
#pragma unroll
        for (int t = 0; t < TOK; t++)
            u_ws[(size_t)(bt0 + t) * Dd + o] = acc[t];
    } else {
        float v0 = V_p[o], v1 = V_p[256 + o];
#pragma unroll
        for (int t = 0; t < TOK; t++) {
            float th = tanhf(acc[t]);
            y0s[t][o] = th * v0;
            y1s[t][o] = th * v1;
        }
    }
    __syncthreads();

    const int wv = tid >> 6;
    float s0 = y0s[wv][ln] + y0s[wv][ln + 64] + y0s[wv][ln + 128] + y0s[wv][ln + 192];
    float s1 = y1s[wv][ln] + y1s[wv][ln + 64] + y1s[wv][ln + 128] + y1s[wv][ln + 192];
#pragma unroll
    for (int of = 32; of >= 1; of >>= 1) {
        s0 += __shfl_xor(s0, of);
        s1 += __shfl_xor(s1, of);
    }
    if (ln == 0) {
        p_ws[(size_t)(bt0 + wv) * 2 + 0] = 128.f / (1.f + expf(-s0));
        p_ws[(size_t)(bt0 + wv) * 2 + 1] = 128.f / (1.f + expf(-s1));
    }
}

// ---------------- Kernel 2: register-resident window attention ------------
// One 512-thread block per token, 16 d-groups x 32 lanes (27 active).
// The gathered window stays in registers (xb[16] float4) from score phase
// through pass 2 — NO LDS window buffer. LDS ~10 KB -> 4 blocks/CU
// (wave-limited), 4-way overlap of the serial per-token chain.
// Pass 2: dense wpos[9][12] weight tile (invalid=0), 16x4 in-register FMA,
// 5-step __shfl_xor reduce over the 32-lane half-group, LDS out staging.
__global__ __launch_bounds__(512, 4) void attn_kernel(
    const float* __restrict__ q,     // (8,256,128,128)
    const float* __restrict__ u_ws,  // (NBT,256)
    const float* __restrict__ p_ws,  // (NBT,2)
    float* __restrict__ out)         // (NBT,256)
{
    __shared__ __align__(16) float pacc_s[16][9][12];   // 6912 B
    __shared__ __align__(16) float wpos[9][12];         // 432 B
    __shared__ float u_s[Dd];
    __shared__ float out_s[Dd];
    __shared__ float a_s[81];
    __shared__ float e_s[81];
    __shared__ float rex_s[9], cex_s[9];
    __shared__ int   rr_s[9], cc_s[9];
    __shared__ float m_sh, inv_sh;

    const int tid = threadIdx.x;
    int bt = blockIdx.x;
    bt = ((bt & 7) << 8) | (bt >> 3);    // batch b -> XCD b (L2 affinity)
    const int b = bt >> 8;

    if (tid < Dd) u_s[tid] = u_ws[(size_t)bt * Dd + tid];
    if (tid < 81) a_s[tid] = -INFINITY;          // prefill: unwritten = invalid

    if (tid < 18) {
        int   i = (tid < 9) ? tid : tid - 9;
        float p = p_ws[(size_t)bt * 2 + ((tid < 9) ? 0 : 1)];
        int base = (int)rintf(p);                 // round-half-even = jnp.round
        int v = base + i - 3;                     // round(p)+off+1, off=i-4
        v = min(max(v, 0), 129) % 129;
        float cl = (float)max(v - 1, 0);
        float z  = (cl - p) * 0.25f;
        float ex = -2.f * z * z;
        if (tid < 9) { rr_s[i] = v; rex_s[i] = ex; }
        else         { cc_s[i] = v; cex_s[i] = ex; }
    }
    __syncthreads();                              // (1)

    // Valid cols form one contiguous run: derive aligned load base (uniform).
    int jc0 = 0, c0 = 1;
#pragma unroll
    for (int j = 8; j >= 0; j--)
        if (cc_s[j] > 0) { jc0 = j; c0 = cc_s[j]; }
    const int cb = min((c0 - 1) & ~3, Ww - 12);   // 12-float window covers run
    const int e0 = (c0 - 1) - cb;

    // ---- gather into registers + fused partial scores ----
    const int g  = tid >> 5;                  // 0..15 d-group
    const int l5 = tid & 31;
    const bool lact = (l5 < 27);
    const int li = lact ? ((l5 * 171) >> 9) : 0;   // l5/3
    const int lv = l5 - li * 3;

    float4 xb[16];                            // the window slice, stays live
    if (lact) {
        const int vr = rr_s[li];
        const int rowoff = (max(vr, 1) - 1) * Ww + cb + 4 * lv;
        const float* qp = q + (size_t)b * Dd * HW + rowoff;
#pragma unroll
        for (int m = 0; m < 16; m++)
            xb[m] = *(const float4*)(qp + (size_t)(g + 16 * m) * HW);

        float px = 0.f, py = 0.f, pz = 0.f, pw = 0.f;
#pragma unroll
        for (int m = 0; m < 16; m++) {
            const float u = u_s[g + 16 * m];
            px = fmaf(xb[m].x, u, px); py = fmaf(xb[m].y, u, py);
            pz = fmaf(xb[m].z, u, pz); pw = fmaf(xb[m].w, u, pw);
        }
        *(float4*)&pacc_s[g][li][4 * lv] = make_float4(px, py, pz, pw);
    }
    __syncthreads();                              // (2)

    // ---- reduce partial scores over 16 d-groups, write valid a_s slots ----
    if (tid < 108) {
        const int lii = tid / 12;
        const int pos = tid - lii * 12;
        float s = 0.f;
#pragma unroll
        for (int gg = 0; gg < 16; gg++) s += pacc_s[gg][lii][pos];
        const int kj = pos - e0 + jc0;            // inverse of pos mapping
        if (kj >= 0 && kj < 9 && rr_s[lii] > 0 && cc_s[kj] > 0)
            a_s[lii * 9 + kj] = s;
    }
    __syncthreads();                              // (3)

    // ---- softmax over 81 (wave-0 butterfly) ----
    if (tid < 64) {
        float m = a_s[tid];
        if (tid + 64 < 81) m = fmaxf(m, a_s[tid + 64]);
        for (int o = 32; o >= 1; o >>= 1) m = fmaxf(m, __shfl_xor(m, o));
        if (tid == 0) m_sh = m;
    }
    __syncthreads();                              // (4)
    if (tid < 81) {
        const float av = a_s[tid];
        e_s[tid] = (av == -INFINITY) ? 0.f : expf(av - m_sh);
    }
    __syncthreads();                              // (5)
    if (tid < 64) {
        float sv = e_s[tid] + ((tid + 64 < 81) ? e_s[tid + 64] : 0.f);
        for (int o = 32; o >= 1; o >>= 1) sv += __shfl_xor(sv, o);
        if (tid == 0) inv_sh = 1.f / sv;
    }
    __syncthreads();                              // (6)

    // ---- dense position-weight tile: wpos[i][pos] (invalid = 0) ----
    if (tid < 108) {
        const int lii = tid / 12;
        const int pos = tid - lii * 12;
        const int kj  = pos - e0 + jc0;
        float w = 0.f;
        if (kj >= 0 && kj < 9 && rr_s[lii] > 0 && cc_s[kj] > 0)
            w = e_s[lii * 9 + kj] * inv_sh * expf(rex_s[lii] + cex_s[kj]);
        wpos[lii][pos] = w;
    }
    __syncthreads();                              // (7)

    // ---- pass 2: in-register FMA + half-group shuffle reduce ----
    float po[16];
    if (lact) {
        const float4 wv = *(const float4*)&wpos[li][4 * lv];
#pragma unroll
        for (int m = 0; m < 16; m++) {
            float acc = xb[m].x * wv.x;
            acc = fmaf(xb[m].y, wv.y, acc);
            acc = fmaf(xb[m].z, wv.z, acc);
            acc = fmaf(xb[m].w, wv.w, acc);
            po[m] = acc;
        }
    } else {
#pragma unroll
        for (int m = 0; m < 16; m++) po[m] = 0.f;
    }
#pragma unroll
    for (int o = 16; o >= 1; o >>= 1) {
#pragma unroll
        for (int m = 0; m < 16; m++) po[m] += __shfl_xor(po[m], o);
    }
    if (l5 == 0) {
#pragma unroll
        for (int m = 0; m < 16; m++) out_s[g + 16 * m] = po[m];
    }
    __syncthreads();                              // (8)
    if (tid < Dd) out[(size_t)bt * Dd + tid] = out_s[tid];
}

extern "C" void kernel_launch(void* const* d_in, const int* in_sizes, int n_in,
                              void* d_out, int out_size, void* d_ws, size_t ws_size,
                              hipStream_t stream) {
    const float* q   = (const float*)d_in[0];
    const float* c_t = (const float*)d_in[1];
    const float* W_a = (const float*)d_in[2];
    const float* W_p = (const float*)d_in[3];
    const float* V_p = (const float*)d_in[4];
    float* out  = (float*)d_out;
    float* u_ws = (float*)d_ws;                       // 2 MB
    float* p_ws = u_ws + (size_t)NBT * Dd;            // 16 KB
    float* WpT  = p_ws + (size_t)NBT * 2;             // 512 KB

    transpose_wp<<<dim3(16, 8), 256, 0, stream>>>(W_p, WpT);
    prep_kernel<<<NBT / TOK, 512, 0, stream>>>(c_t, W_a, WpT, V_p, u_ws, p_ws);
    attn_kernel<<<NBT, 512, 0, stream>>>(q, u_ws, p_ws, out);
}

// Round 7
// 262.725 us; speedup vs baseline: 1.4760x; 1.4760x over previous
//
#include <hip/hip_runtime.h>
#include <math.h>

// Shapes (fixed): q(8,256,128,128) c_t(8,256,512) W_a(512,256) W_p(256,512) V_p(2,256)
#define Bq 8
#define Tt 256
#define Dd 256
#define Hh 128
#define Ww 128
#define Cc 512
#define HW (Hh*Ww)
#define NBT (Bq*Tt)   // 2048 tokens

__device__ __forceinline__ float lane_bcast(float x, int l) {
    return __uint_as_float(__builtin_amdgcn_readlane(__float_as_uint(x), l));
}

// ---------------- Kernel 0: transpose W_p (256x512) -> WpT (512x256) ------
__global__ __launch_bounds__(256) void transpose_wp(
    const float* __restrict__ W_p, float* __restrict__ WpT)
{
    __shared__ float tile[32][33];
    const int bx = blockIdx.x;            // c tile (16)
    const int by = blockIdx.y;            // p tile (8)
    const int lx = threadIdx.x & 31, ly = threadIdx.x >> 5;   // 32 x 8
#pragma unroll
    for (int j = 0; j < 4; j++) {
        int p = by * 32 + ly + j * 8;
        tile[ly + j * 8][lx] = W_p[(size_t)p * Cc + bx * 32 + lx];
    }
    __syncthreads();
#pragma unroll
    for (int j = 0; j < 4; j++) {
        int c = bx * 32 + ly + j * 8;
        WpT[(size_t)c * 256 + by * 32 + lx] = tile[lx][ly + j * 8];
    }
}

// ---------------- Kernel 1: u = c_t@W_a, p_t = 128*sig(V_p tanh(W_p c)) ---
// r6 PMC: 84% stall (VALUBusy 16%) — weight-load latency exposed at
// 2 waves/SIMD with no prefetch. Fix: TOK=4 -> 512 blocks (2/CU,
// 4 waves/SIMD) + double-buffered weight prefetch (wn[8] for chunk k+1
// issued before chunk k's FMA block). VGPR ~50, bounds (512,3) keeps
// 4 waves/SIMD resident.
#define TOK 4
__global__ __launch_bounds__(512, 3) void prep_kernel(
    const float* __restrict__ c_t,   // (NBT, 512)
    const float* __restrict__ W_a,   // (512, 256)  [c][d]
    const float* __restrict__ WpT,   // (512, 256)  [c][p]
    const float* __restrict__ V_p,   // (2, 256)
    float* __restrict__ u_ws,        // (NBT, 256)
    float* __restrict__ p_ws)        // (NBT, 2)
{
    __shared__ float y0s[TOK][256];
    __shared__ float y1s[TOK][256];
    const int tid  = threadIdx.x;
    const int o    = tid & 255;
    const int half = tid >> 8;
    const int ln   = tid & 63;
    const int bt0  = blockIdx.x * TOK;

    const float* Wcol = (half ? WpT : W_a) + o;   // column o, stride 256
    const float* ctb  = c_t + (size_t)bt0 * Cc;

    float acc[TOK];
#pragma unroll
    for (int t = 0; t < TOK; t++) acc[t] = 0.f;

    float ctr[TOK], ctn[TOK];
#pragma unroll
    for (int t = 0; t < TOK; t++) ctr[t] = ctb[t * Cc + ln];

    // preload weight chunk 0
    float w[8];
#pragma unroll
    for (int j = 0; j < 8; j++) w[j] = Wcol[(size_t)j * 256];

#pragma unroll
    for (int c0 = 0; c0 < Cc; c0 += 64) {
        if (c0 + 64 < Cc) {
#pragma unroll
            for (int t = 0; t < TOK; t++) ctn[t] = ctb[t * Cc + c0 + 64 + ln];
        }
#pragma unroll
        for (int cc8 = 0; cc8 < 64; cc8 += 8) {
            // prefetch next weight chunk while current FMAs run
            float wn[8];
            const int nc = c0 + cc8 + 8;
            const bool hasn = (nc < Cc);
            if (hasn) {
#pragma unroll
                for (int j = 0; j < 8; j++)
                    wn[j] = Wcol[(size_t)(nc + j) * 256];
            }
#pragma unroll
            for (int j = 0; j < 8; j++) {
#pragma unroll
                for (int t = 0; t < TOK; t++)
                    acc[t] = fmaf(lane_bcast(ctr[t], cc8 + j), w[j], acc[t]);
            }
            if (hasn) {
#pragma unroll
                for (int j = 0; j < 8; j++) w[j] = wn[j];
            }
        }
#pragma unroll
        for (int t = 0; t < TOK; t++) ctr[t] = ctn[t];
    }

    if (half == 0) {
#pragma unroll
        for (int t = 0; t < TOK; t++)
            u_ws[(size_t)(bt0 + t) * Dd + o] = acc[t];
    } else {
        float v0 = V_p[o], v1 = V_p[256 + o];
#pragma unroll
        for (int t = 0; t < TOK; t++) {
            float th = tanhf(acc[t]);
            y0s[t][o] = th * v0;
            y1s[t][o] = th * v1;
        }
    }
    __syncthreads();

    // waves 0..TOK-1: wave w reduces token w (both outputs).
    const int wv = tid >> 6;
    if (wv < TOK) {
        float s0 = y0s[wv][ln] + y0s[wv][ln + 64] + y0s[wv][ln + 128] + y0s[wv][ln + 192];
        float s1 = y1s[wv][ln] + y1s[wv][ln + 64] + y1s[wv][ln + 128] + y1s[wv][ln + 192];
#pragma unroll
        for (int of = 32; of >= 1; of >>= 1) {
            s0 += __shfl_xor(s0, of);
            s1 += __shfl_xor(s1, of);
        }
        if (ln == 0) {
            p_ws[(size_t)(bt0 + wv) * 2 + 0] = 128.f / (1.f + expf(-s0));
            p_ws[(size_t)(bt0 + wv) * 2 + 1] = 128.f / (1.f + expf(-s1));
        }
    }
}

// ---------------- Kernel 2: register-resident window attention ------------
// One 512-thread block per token, 16 d-groups x 32 lanes (27 active).
// The gathered window stays in registers (xb[16] float4) from score phase
// through pass 2 — NO LDS window buffer. LDS ~10 KB -> 4 blocks/CU
// (wave-limited), 4-way overlap of the serial per-token chain.
// Pass 2: dense wpos[9][12] weight tile (invalid=0), 16x4 in-register FMA,
// 5-step __shfl_xor reduce over the 32-lane half-group, LDS out staging.
__global__ __launch_bounds__(512, 4) void attn_kernel(
    const float* __restrict__ q,     // (8,256,128,128)
    const float* __restrict__ u_ws,  // (NBT,256)
    const float* __restrict__ p_ws,  // (NBT,2)
    float* __restrict__ out)         // (NBT,256)
{
    __shared__ __align__(16) float pacc_s[16][9][12];   // 6912 B
    __shared__ __align__(16) float wpos[9][12];         // 432 B
    __shared__ float u_s[Dd];
    __shared__ float out_s[Dd];
    __shared__ float a_s[81];
    __shared__ float e_s[81];
    __shared__ float rex_s[9], cex_s[9];
    __shared__ int   rr_s[9], cc_s[9];
    __shared__ float m_sh, inv_sh;

    const int tid = threadIdx.x;
    int bt = blockIdx.x;
    bt = ((bt & 7) << 8) | (bt >> 3);    // batch b -> XCD b (L2 affinity)
    const int b = bt >> 8;

    if (tid < Dd) u_s[tid] = u_ws[(size_t)bt * Dd + tid];
    if (tid < 81) a_s[tid] = -INFINITY;          // prefill: unwritten = invalid

    if (tid < 18) {
        int   i = (tid < 9) ? tid : tid - 9;
        float p = p_ws[(size_t)bt * 2 + ((tid < 9) ? 0 : 1)];
        int base = (int)rintf(p);                 // round-half-even = jnp.round
        int v = base + i - 3;                     // round(p)+off+1, off=i-4
        v = min(max(v, 0), 129) % 129;
        float cl = (float)max(v - 1, 0);
        float z  = (cl - p) * 0.25f;
        float ex = -2.f * z * z;
        if (tid < 9) { rr_s[i] = v; rex_s[i] = ex; }
        else         { cc_s[i] = v; cex_s[i] = ex; }
    }
    __syncthreads();                              // (1)

    // Valid cols form one contiguous run: derive aligned load base (uniform).
    int jc0 = 0, c0 = 1;
#pragma unroll
    for (int j = 8; j >= 0; j--)
        if (cc_s[j] > 0) { jc0 = j; c0 = cc_s[j]; }
    const int cb = min((c0 - 1) & ~3, Ww - 12);   // 12-float window covers run
    const int e0 = (c0 - 1) - cb;

    // ---- gather into registers + fused partial scores ----
    const int g  = tid >> 5;                  // 0..15 d-group
    const int l5 = tid & 31;
    const bool lact = (l5 < 27);
    const int li = lact ? ((l5 * 171) >> 9) : 0;   // l5/3
    const int lv = l5 - li * 3;

    float4 xb[16];                            // the window slice, stays live
    if (lact) {
        const int vr = rr_s[li];
        const int rowoff = (max(vr, 1) - 1) * Ww + cb + 4 * lv;
        const float* qp = q + (size_t)b * Dd * HW + rowoff;
#pragma unroll
        for (int m = 0; m < 16; m++)
            xb[m] = *(const float4*)(qp + (size_t)(g + 16 * m) * HW);

        float px = 0.f, py = 0.f, pz = 0.f, pw = 0.f;
#pragma unroll
        for (int m = 0; m < 16; m++) {
            const float u = u_s[g + 16 * m];
            px = fmaf(xb[m].x, u, px); py = fmaf(xb[m].y, u, py);
            pz = fmaf(xb[m].z, u, pz); pw = fmaf(xb[m].w, u, pw);
        }
        *(float4*)&pacc_s[g][li][4 * lv] = make_float4(px, py, pz, pw);
    }
    __syncthreads();                              // (2)

    // ---- reduce partial scores over 16 d-groups, write valid a_s slots ----
    if (tid < 108) {
        const int lii = tid / 12;
        const int pos = tid - lii * 12;
        float s = 0.f;
#pragma unroll
        for (int gg = 0; gg < 16; gg++) s += pacc_s[gg][lii][pos];
        const int kj = pos - e0 + jc0;            // inverse of pos mapping
        if (kj >= 0 && kj < 9 && rr_s[lii] > 0 && cc_s[kj] > 0)
            a_s[lii * 9 + kj] = s;
    }
    __syncthreads();                              // (3)

    // ---- softmax over 81 (wave-0 butterfly) ----
    if (tid < 64) {
        float m = a_s[tid];
        if (tid + 64 < 81) m = fmaxf(m, a_s[tid + 64]);
        for (int o = 32; o >= 1; o >>= 1) m = fmaxf(m, __shfl_xor(m, o));
        if (tid == 0) m_sh = m;
    }
    __syncthreads();                              // (4)
    if (tid < 81) {
        const float av = a_s[tid];
        e_s[tid] = (av == -INFINITY) ? 0.f : expf(av - m_sh);
    }
    __syncthreads();                              // (5)
    if (tid < 64) {
        float sv = e_s[tid] + ((tid + 64 < 81) ? e_s[tid + 64] : 0.f);
        for (int o = 32; o >= 1; o >>= 1) sv += __shfl_xor(sv, o);
        if (tid == 0) inv_sh = 1.f / sv;
    }
    __syncthreads();                              // (6)

    // ---- dense position-weight tile: wpos[i][pos] (invalid = 0) ----
    if (tid < 108) {
        const int lii = tid / 12;
        const int pos = tid - lii * 12;
        const int kj  = pos - e0 + jc0;
        float w = 0.f;
        if (kj >= 0 && kj < 9 && rr_s[lii] > 0 && cc_s[kj] > 0)
            w = e_s[lii * 9 + kj] * inv_sh * expf(rex_s[lii] + cex_s[kj]);
        wpos[lii][pos] = w;
    }
    __syncthreads();                              // (7)

    // ---- pass 2: in-register FMA + half-group shuffle reduce ----
    float po[16];
    if (lact) {
        const float4 wv = *(const float4*)&wpos[li][4 * lv];
#pragma unroll
        for (int m = 0; m < 16; m++) {
            float acc = xb[m].x * wv.x;
            acc = fmaf(xb[m].y, wv.y, acc);
            acc = fmaf(xb[m].z, wv.z, acc);
            acc = fmaf(xb[m].w, wv.w, acc);
            po[m] = acc;
        }
    } else {
#pragma unroll
        for (int m = 0; m < 16; m++) po[m] = 0.f;
    }
#pragma unroll
    for (int o = 16; o >= 1; o >>= 1) {
#pragma unroll
        for (int m = 0; m < 16; m++) po[m] += __shfl_xor(po[m], o);
    }
    if (l5 == 0) {
#pragma unroll
        for (int m = 0; m < 16; m++) out_s[g + 16 * m] = po[m];
    }
    __syncthreads();                              // (8)
    if (tid < Dd) out[(size_t)bt * Dd + tid] = out_s[tid];
}

extern "C" void kernel_launch(void* const* d_in, const int* in_sizes, int n_in,
                              void* d_out, int out_size, void* d_ws, size_t ws_size,
                              hipStream_t stream) {
    const float* q   = (const float*)d_in[0];
    const float* c_t = (const float*)d_in[1];
    const float* W_a = (const float*)d_in[2];
    const float* W_p = (const float*)d_in[3];
    const float* V_p = (const float*)d_in[4];
    float* out  = (float*)d_out;
    float* u_ws = (float*)d_ws;                       // 2 MB
    float* p_ws = u_ws + (size_t)NBT * Dd;            // 16 KB
    float* WpT  = p_ws + (size_t)NBT * 2;             // 512 KB

    transpose_wp<<<dim3(16, 8), 256, 0, stream>>>(W_p, WpT);
    prep_kernel<<<NBT / TOK, 512, 0, stream>>>(c_t, W_a, WpT, V_p, u_ws, p_ws);
    attn_kernel<<<NBT, 512, 0, stream>>>(q, u_ws, p_ws, out);
}

// Round 8
// 250.100 us; speedup vs baseline: 1.5505x; 1.0505x over previous
//
#include <hip/hip_runtime.h>
#include <math.h>

// Shapes (fixed): q(8,256,128,128) c_t(8,256,512) W_a(512,256) W_p(256,512) V_p(2,256)
#define Bq 8
#define Tt 256
#define Dd 256
#define Hh 128
#define Ww 128
#define Cc 512
#define HW (Hh*Ww)
#define NBT (Bq*Tt)   // 2048 tokens

__device__ __forceinline__ float lane_bcast(float x, int l) {
    return __uint_as_float(__builtin_amdgcn_readlane(__float_as_uint(x), l));
}

// ---------------- Kernel 0: transpose W_p (256x512) -> WpT (512x256) ------
__global__ __launch_bounds__(256) void transpose_wp(
    const float* __restrict__ W_p, float* __restrict__ WpT)
{
    __shared__ float tile[32][33];
    const int bx = blockIdx.x;            // c tile (16)
    const int by = blockIdx.y;            // p tile (8)
    const int lx = threadIdx.x & 31, ly = threadIdx.x >> 5;   // 32 x 8
#pragma unroll
    for (int j = 0; j < 4; j++) {
        int p = by * 32 + ly + j * 8;
        tile[ly + j * 8][lx] = W_p[(size_t)p * Cc + bx * 32 + lx];
    }
    __syncthreads();
#pragma unroll
    for (int j = 0; j < 4; j++) {
        int c = bx * 32 + ly + j * 8;
        WpT[(size_t)c * 256 + by * 32 + lx] = tile[lx][ly + j * 8];
    }
}

// ---------------- Kernel 1: u = c_t@W_a, p_t = 128*sig(V_p tanh(W_p c)) ---
// r7 null (TOK/prefetch) proves the stall is per-instruction: 4B weight
// loads (256B/wave) + 1 readlane per FMA. Rework: thread owns 4 output
// columns (float4 weight loads = 1KB/wave) x K-quarter (split-K x4 in
// block, ct fully register-resident, 1 readlane per 4 FMAs). Ping-pong
// 8-row chunks keep 8 loads in flight under ~320cy VALU. 512 blocks,
// 2/CU, 4 waves/SIMD. 32KB LDS split-K reduce + original p-epilogue.
#define TOKP 4

#define LOAD8(BUF, BASE) \
    { _Pragma("unroll") for (int j = 0; j < 8; j++) \
        BUF[j] = *(const float4*)(Wk + (size_t)((BASE) + j) * 256); }

#define FMA8(BUF, BASE, CT) \
    { _Pragma("unroll") for (int j = 0; j < 8; j++) { \
        _Pragma("unroll") for (int t = 0; t < TOKP; t++) { \
            const float cv = lane_bcast(CT[t], ((BASE) + j) & 63); \
            acc[t].x = fmaf(cv, BUF[j].x, acc[t].x); \
            acc[t].y = fmaf(cv, BUF[j].y, acc[t].y); \
            acc[t].z = fmaf(cv, BUF[j].z, acc[t].z); \
            acc[t].w = fmaf(cv, BUF[j].w, acc[t].w); } } }

__global__ __launch_bounds__(512, 4) void prep_kernel(
    const float* __restrict__ c_t,   // (NBT, 512)
    const float* __restrict__ W_a,   // (512, 256)  [c][d]
    const float* __restrict__ WpT,   // (512, 256)  [c][p]
    const float* __restrict__ V_p,   // (2, 256)
    float* __restrict__ u_ws,        // (NBT, 256)
    float* __restrict__ p_ws)        // (NBT, 2)
{
    __shared__ __align__(16) float pacc_l[4][TOKP][512];   // 32 KB
    __shared__ float y0s[TOKP][256];                       // 4 KB
    __shared__ float y1s[TOKP][256];                       // 4 KB

    const int tid = threadIdx.x;
    const int ln  = tid & 63;
    const int kq  = tid >> 7;                // K-quarter 0..3
    const int mat = (tid >> 6) & 1;          // 0: W_a, 1: WpT
    const int cw  = ln << 2;                 // 4-col base within matrix
    const int bt0 = blockIdx.x * TOKP;

    const float* Wk  = (mat ? WpT : W_a) + cw + (size_t)(kq * 128) * 256;
    const float* ctb = c_t + (size_t)bt0 * Cc + kq * 128;

    // ct for this K-quarter, fully register-resident (2 regs/token)
    float ct0[TOKP], ct1[TOKP];
#pragma unroll
    for (int t = 0; t < TOKP; t++) {
        ct0[t] = ctb[t * Cc + ln];
        ct1[t] = ctb[t * Cc + 64 + ln];
    }

    float4 acc[TOKP];
#pragma unroll
    for (int t = 0; t < TOKP; t++) acc[t] = make_float4(0.f, 0.f, 0.f, 0.f);

    float4 wa[8], wb[8];
    LOAD8(wa, 0)
    LOAD8(wb, 8);   FMA8(wa, 0,   ct0)
    LOAD8(wa, 16);  FMA8(wb, 8,   ct0)
    LOAD8(wb, 24);  FMA8(wa, 16,  ct0)
    LOAD8(wa, 32);  FMA8(wb, 24,  ct0)
    LOAD8(wb, 40);  FMA8(wa, 32,  ct0)
    LOAD8(wa, 48);  FMA8(wb, 40,  ct0)
    LOAD8(wb, 56);  FMA8(wa, 48,  ct0)
    LOAD8(wa, 64);  FMA8(wb, 56,  ct0)
    LOAD8(wb, 72);  FMA8(wa, 64,  ct1)
    LOAD8(wa, 80);  FMA8(wb, 72,  ct1)
    LOAD8(wb, 88);  FMA8(wa, 80,  ct1)
    LOAD8(wa, 96);  FMA8(wb, 88,  ct1)
    LOAD8(wb, 104); FMA8(wa, 96,  ct1)
    LOAD8(wa, 112); FMA8(wb, 104, ct1)
    LOAD8(wb, 120); FMA8(wa, 112, ct1)
    FMA8(wb, 120, ct1)

    // split-K partials -> LDS (float4 stores, conflict-free)
#pragma unroll
    for (int t = 0; t < TOKP; t++)
        *(float4*)&pacc_l[kq][t][mat * 256 + cw] = acc[t];
    __syncthreads();

    // reduce 4 K-quarters; cols<256 -> u, cols>=256 -> tanh*V_p staging
#pragma unroll
    for (int i = 0; i < TOKP; i++) {
        const int col = tid & 511;               // == tid
        float s = pacc_l[0][i][col] + pacc_l[1][i][col]
                + pacc_l[2][i][col] + pacc_l[3][i][col];
        if (col < 256) {
            u_ws[(size_t)(bt0 + i) * Dd + col] = s;
        } else {
            const int o = col - 256;
            const float th = tanhf(s);
            y0s[i][o] = th * V_p[o];
            y1s[i][o] = th * V_p[256 + o];
        }
    }
    __syncthreads();

    // p_t: wave w -> token w&3, component w>>2
    const int wv = tid >> 6;
    const int tk = wv & 3;
    const float* ys = (wv >> 2) ? &y1s[tk][0] : &y0s[tk][0];
    float s = ys[ln] + ys[ln + 64] + ys[ln + 128] + ys[ln + 192];
#pragma unroll
    for (int of = 32; of >= 1; of >>= 1) s += __shfl_xor(s, of);
    if (ln == 0)
        p_ws[(size_t)(bt0 + tk) * 2 + (wv >> 2)] = 128.f / (1.f + expf(-s));
}

// ---------------- Kernel 2: register-resident window attention ------------
// (unchanged from r7: 512 thr/token, window in registers, ~22 us, near its
//  18 us compulsory-fetch floor)
__global__ __launch_bounds__(512, 4) void attn_kernel(
    const float* __restrict__ q,     // (8,256,128,128)
    const float* __restrict__ u_ws,  // (NBT,256)
    const float* __restrict__ p_ws,  // (NBT,2)
    float* __restrict__ out)         // (NBT,256)
{
    __shared__ __align__(16) float pacc_s[16][9][12];   // 6912 B
    __shared__ __align__(16) float wpos[9][12];         // 432 B
    __shared__ float u_s[Dd];
    __shared__ float out_s[Dd];
    __shared__ float a_s[81];
    __shared__ float e_s[81];
    __shared__ float rex_s[9], cex_s[9];
    __shared__ int   rr_s[9], cc_s[9];
    __shared__ float m_sh, inv_sh;

    const int tid = threadIdx.x;
    int bt = blockIdx.x;
    bt = ((bt & 7) << 8) | (bt >> 3);    // batch b -> XCD b (L2 affinity)
    const int b = bt >> 8;

    if (tid < Dd) u_s[tid] = u_ws[(size_t)bt * Dd + tid];
    if (tid < 81) a_s[tid] = -INFINITY;          // prefill: unwritten = invalid

    if (tid < 18) {
        int   i = (tid < 9) ? tid : tid - 9;
        float p = p_ws[(size_t)bt * 2 + ((tid < 9) ? 0 : 1)];
        int base = (int)rintf(p);                 // round-half-even = jnp.round
        int v = base + i - 3;                     // round(p)+off+1, off=i-4
        v = min(max(v, 0), 129) % 129;
        float cl = (float)max(v - 1, 0);
        float z  = (cl - p) * 0.25f;
        float ex = -2.f * z * z;
        if (tid < 9) { rr_s[i] = v; rex_s[i] = ex; }
        else         { cc_s[i] = v; cex_s[i] = ex; }
    }
    __syncthreads();                              // (1)

    // Valid cols form one contiguous run: derive aligned load base (uniform).
    int jc0 = 0, c0 = 1;
#pragma unroll
    for (int j = 8; j >= 0; j--)
        if (cc_s[j] > 0) { jc0 = j; c0 = cc_s[j]; }
    const int cb = min((c0 - 1) & ~3, Ww - 12);   // 12-float window covers run
    const int e0 = (c0 - 1) - cb;

    // ---- gather into registers + fused partial scores ----
    const int g  = tid >> 5;                  // 0..15 d-group
    const int l5 = tid & 31;
    const bool lact = (l5 < 27);
    const int li = lact ? ((l5 * 171) >> 9) : 0;   // l5/3
    const int lv = l5 - li * 3;

    float4 xb[16];                            // the window slice, stays live
    if (lact) {
        const int vr = rr_s[li];
        const int rowoff = (max(vr, 1) - 1) * Ww + cb + 4 * lv;
        const float* qp = q + (size_t)b * Dd * HW + rowoff;
#pragma unroll
        for (int m = 0; m < 16; m++)
            xb[m] = *(const float4*)(qp + (size_t)(g + 16 * m) * HW);

        float px = 0.f, py = 0.f, pz = 0.f, pw = 0.f;
#pragma unroll
        for (int m = 0; m < 16; m++) {
            const float u = u_s[g + 16 * m];
            px = fmaf(xb[m].x, u, px); py = fmaf(xb[m].y, u, py);
            pz = fmaf(xb[m].z, u, pz); pw = fmaf(xb[m].w, u, pw);
        }
        *(float4*)&pacc_s[g][li][4 * lv] = make_float4(px, py, pz, pw);
    }
    __syncthreads();                              // (2)

    // ---- reduce partial scores over 16 d-groups, write valid a_s slots ----
    if (tid < 108) {
        const int lii = tid / 12;
        const int pos = tid - lii * 12;
        float s = 0.f;
#pragma unroll
        for (int gg = 0; gg < 16; gg++) s += pacc_s[gg][lii][pos];
        const int kj = pos - e0 + jc0;            // inverse of pos mapping
        if (kj >= 0 && kj < 9 && rr_s[lii] > 0 && cc_s[kj] > 0)
            a_s[lii * 9 + kj] = s;
    }
    __syncthreads();                              // (3)

    // ---- softmax over 81 (wave-0 butterfly) ----
    if (tid < 64) {
        float m = a_s[tid];
        if (tid + 64 < 81) m = fmaxf(m, a_s[tid + 64]);
        for (int o = 32; o >= 1; o >>= 1) m = fmaxf(m, __shfl_xor(m, o));
        if (tid == 0) m_sh = m;
    }
    __syncthreads();                              // (4)
    if (tid < 81) {
        const float av = a_s[tid];
        e_s[tid] = (av == -INFINITY) ? 0.f : expf(av - m_sh);
    }
    __syncthreads();                              // (5)
    if (tid < 64) {
        float sv = e_s[tid] + ((tid + 64 < 81) ? e_s[tid + 64] : 0.f);
        for (int o = 32; o >= 1; o >>= 1) sv += __shfl_xor(sv, o);
        if (tid == 0) inv_sh = 1.f / sv;
    }
    __syncthreads();                              // (6)

    // ---- dense position-weight tile: wpos[i][pos] (invalid = 0) ----
    if (tid < 108) {
        const int lii = tid / 12;
        const int pos = tid - lii * 12;
        const int kj  = pos - e0 + jc0;
        float w = 0.f;
        if (kj >= 0 && kj < 9 && rr_s[lii] > 0 && cc_s[kj] > 0)
            w = e_s[lii * 9 + kj] * inv_sh * expf(rex_s[lii] + cex_s[kj]);
        wpos[lii][pos] = w;
    }
    __syncthreads();                              // (7)

    // ---- pass 2: in-register FMA + half-group shuffle reduce ----
    float po[16];
    if (lact) {
        const float4 wv = *(const float4*)&wpos[li][4 * lv];
#pragma unroll
        for (int m = 0; m < 16; m++) {
            float acc = xb[m].x * wv.x;
            acc = fmaf(xb[m].y, wv.y, acc);
            acc = fmaf(xb[m].z, wv.z, acc);
            acc = fmaf(xb[m].w, wv.w, acc);
            po[m] = acc;
        }
    } else {
#pragma unroll
        for (int m = 0; m < 16; m++) po[m] = 0.f;
    }
#pragma unroll
    for (int o = 16; o >= 1; o >>= 1) {
#pragma unroll
        for (int m = 0; m < 16; m++) po[m] += __shfl_xor(po[m], o);
    }
    if (l5 == 0) {
#pragma unroll
        for (int m = 0; m < 16; m++) out_s[g + 16 * m] = po[m];
    }
    __syncthreads();                              // (8)
    if (tid < Dd) out[(size_t)bt * Dd + tid] = out_s[tid];
}

extern "C" void kernel_launch(void* const* d_in, const int* in_sizes, int n_in,
                              void* d_out, int out_size, void* d_ws, size_t ws_size,
                              hipStream_t stream) {
    const float* q   = (const float*)d_in[0];
    const float* c_t = (const float*)d_in[1];
    const float* W_a = (const float*)d_in[2];
    const float* W_p = (const float*)d_in[3];
    const float* V_p = (const float*)d_in[4];
    float* out  = (float*)d_out;
    float* u_ws = (float*)d_ws;                       // 2 MB
    float* p_ws = u_ws + (size_t)NBT * Dd;            // 16 KB
    float* WpT  = p_ws + (size_t)NBT * 2;             // 512 KB

    transpose_wp<<<dim3(16, 8), 256, 0, stream>>>(W_p, WpT);
    prep_kernel<<<NBT / TOKP, 512, 0, stream>>>(c_t, W_a, WpT, V_p, u_ws, p_ws);
    attn_kernel<<<NBT, 512, 0, stream>>>(q, u_ws, p_ws, out);
}